// Round 1
// baseline (2523.141 us; speedup 1.0000x reference)
//
#include <hip/hip_runtime.h>
#include <hip/hip_bf16.h>

#define HN 128
#define EPS 1e-5f

// ---------------- GEMM: m = relu(x @ W^T + b) ----------------
// One thread per output column o (block=128). W[o][:] held in registers
// (32 x float4 = 128 VGPR). 8 rows per iteration staged in LDS, read back
// as broadcast float4 (ds_read_b128, same-address broadcast = cheap).
__global__ __launch_bounds__(128) void gemm_relu_k(
    const float* __restrict__ x, const float* __restrict__ W,
    const float* __restrict__ b, float* __restrict__ m, int nrows) {
  const int o = threadIdx.x;  // 0..127
  float4 w4[32];
#pragma unroll
  for (int j = 0; j < 32; ++j)
    w4[j] = *reinterpret_cast<const float4*>(&W[o * HN + 4 * j]);
  const float bias = b[o];

  __shared__ float xs[8][HN];  // 4 KB

  for (int r0 = blockIdx.x * 8; r0 < nrows; r0 += gridDim.x * 8) {
    const int nr = min(8, nrows - r0);
    __syncthreads();
    if (nr == 8) {
      // 8 rows = 1024 floats contiguous; 128 threads x 2 float4
      float4 v0 = *reinterpret_cast<const float4*>(&x[(size_t)r0 * HN + threadIdx.x * 4]);
      float4 v1 = *reinterpret_cast<const float4*>(&x[(size_t)r0 * HN + 512 + threadIdx.x * 4]);
      reinterpret_cast<float4*>(xs)[threadIdx.x] = v0;
      reinterpret_cast<float4*>(xs)[threadIdx.x + 128] = v1;
    } else {
      for (int t = threadIdx.x; t < nr * HN; t += blockDim.x)
        reinterpret_cast<float*>(xs)[t] = x[(size_t)r0 * HN + t];
    }
    __syncthreads();

    float acc[8];
#pragma unroll
    for (int r = 0; r < 8; ++r) acc[r] = bias;

#pragma unroll
    for (int k4 = 0; k4 < 32; ++k4) {
      const float4 wv = w4[k4];
#pragma unroll
      for (int r = 0; r < 8; ++r) {
        const float4 xv = *reinterpret_cast<const float4*>(&xs[r][k4 * 4]);
        acc[r] = fmaf(xv.x, wv.x, acc[r]);
        acc[r] = fmaf(xv.y, wv.y, acc[r]);
        acc[r] = fmaf(xv.z, wv.z, acc[r]);
        acc[r] = fmaf(xv.w, wv.w, acc[r]);
      }
    }
#pragma unroll
    for (int r = 0; r < 8; ++r) {
      if (r < nr) m[(size_t)(r0 + r) * HN + o] = fmaxf(acc[r], 0.f);
    }
  }
}

// ---------------- degree histogram ----------------
__global__ void degree_k(const int* __restrict__ rows, int* __restrict__ deg,
                         int nedges) {
  for (int e = blockIdx.x * blockDim.x + threadIdx.x; e < nedges;
       e += gridDim.x * blockDim.x)
    atomicAdd(&deg[rows[e]], 1);
}

// ---------------- edge scatter: agg[rows[e]] += m[cols[e]] ----------------
__global__ void scatter_k(const float* __restrict__ m,
                          const int* __restrict__ rows,
                          const int* __restrict__ cols,
                          float* __restrict__ agg, int nedges) {
  const long long total = (long long)nedges * HN;
  for (long long i = (long long)blockIdx.x * blockDim.x + threadIdx.x;
       i < total; i += (long long)gridDim.x * blockDim.x) {
    const int e = (int)(i >> 7);
    const int c = (int)(i & (HN - 1));
    const int r = rows[e];
    const int col = cols[e];
    unsafeAtomicAdd(&agg[(size_t)r * HN + c], m[(size_t)col * HN + c]);
  }
}

// ---------------- finalize: h = x + agg/d; RMSNorm ----------------
__global__ __launch_bounds__(256) void finalize_k(
    const float* __restrict__ x, const float* __restrict__ gamma,
    const float* __restrict__ beta, const int* __restrict__ deg,
    float* __restrict__ out, int nrows) {
  const int wave = threadIdx.x >> 6;
  const int lane = threadIdx.x & 63;
  for (int r = blockIdx.x * 4 + wave; r < nrows; r += gridDim.x * 4) {
    const size_t base = (size_t)r * HN + lane * 2;
    const float2 xa = *reinterpret_cast<const float2*>(&x[base]);
    const float2 ag = *reinterpret_cast<const float2*>(&out[base]);
    const int d = deg[r];
    const float inv_d = d > 0 ? 1.f / (float)d : 1.f;
    const float h0 = xa.x + ag.x * inv_d;
    const float h1 = xa.y + ag.y * inv_d;
    float ss = h0 * h0 + h1 * h1;
#pragma unroll
    for (int off = 1; off < 64; off <<= 1) ss += __shfl_xor(ss, off);
    const float invrms = rsqrtf(ss * (1.f / HN) + EPS);
    const float g0 = gamma[lane * 2], g1 = gamma[lane * 2 + 1];
    const float b0 = beta[lane * 2], b1 = beta[lane * 2 + 1];
    float2 o2;
    o2.x = h0 * invrms * g0 + b0;
    o2.y = h1 * invrms * g1 + b1;
    *reinterpret_cast<float2*>(&out[base]) = o2;
  }
}

extern "C" void kernel_launch(void* const* d_in, const int* in_sizes, int n_in,
                              void* d_out, int out_size, void* d_ws,
                              size_t ws_size, hipStream_t stream) {
  const float* x = (const float*)d_in[0];
  const float* W = (const float*)d_in[1];
  const float* b = (const float*)d_in[2];
  const float* gamma = (const float*)d_in[3];
  const float* beta = (const float*)d_in[4];
  const int* rows = (const int*)d_in[5];
  const int* cols = (const int*)d_in[6];
  float* out = (float*)d_out;

  const int N = in_sizes[0] / HN;  // 100000
  const int E = in_sizes[5];       // 1600000

  float* m = (float*)d_ws;                                   // N*HN f32
  int* deg = (int*)((char*)d_ws + (size_t)N * HN * sizeof(float));  // N i32

  // agg accumulates in d_out; zero it and the degree array each call.
  hipMemsetAsync(out, 0, (size_t)N * HN * sizeof(float), stream);
  hipMemsetAsync(deg, 0, (size_t)N * sizeof(int), stream);

  gemm_relu_k<<<2048, 128, 0, stream>>>(x, W, b, m, N);
  degree_k<<<1024, 256, 0, stream>>>(rows, deg, E);
  scatter_k<<<16384, 256, 0, stream>>>(m, rows, cols, out, E);
  finalize_k<<<4096, 256, 0, stream>>>(x, gamma, beta, deg, out, N);
}

// Round 2
// 665.075 us; speedup vs baseline: 3.7938x; 3.7938x over previous
//
#include <hip/hip_runtime.h>
#include <hip/hip_bf16.h>

#define HN 128
#define EPS 1e-5f

// ---------------- GEMM: m = relu(x @ W^T + b), output bf16 ----------------
// Block = 256 threads: o = tid&127 (output column), g = tid>>7 (row half).
// W staged in LDS as float4 with XOR swizzle (c ^ (o&7)) -> conflict-free
// ds_read_b128 when all 128 o-threads read their own W row at the same k4.
// x rows staged in LDS, read as same-address broadcast (free).
// 16 accumulators/thread; ~40 VGPR -> no spill (R1 failure mode: 256 VGPR,
// 6 GB scratch traffic).
__global__ __launch_bounds__(256) void gemm_relu_k(
    const float* __restrict__ x, const float* __restrict__ W,
    const float* __restrict__ bias, __hip_bfloat16* __restrict__ m,
    int nrows) {
  __shared__ float4 Wl[128 * 32];  // 64 KB, swizzled
  __shared__ float4 xl[32 * 32];   // 16 KB, 32 rows
  const int t = threadIdx.x;
  const int o = t & 127;
  const int g = t >> 7;

  // stage W (swizzled)
  for (int f = t; f < 128 * 32; f += 256) {
    const int ro = f >> 5, c = f & 31;
    Wl[ro * 32 + (c ^ (ro & 7))] = reinterpret_cast<const float4*>(W)[f];
  }
  const float bo = bias[o];

  const int r0 = blockIdx.x * 32;
  if (r0 >= nrows) return;
  const int nr = min(32, nrows - r0);

  if (nr == 32) {
    for (int f = t; f < 32 * 32; f += 256)
      xl[f] = reinterpret_cast<const float4*>(x + (size_t)r0 * HN)[f];
  } else {
    for (int f = t; f < 32 * 32; f += 256) {
      const int rr = f >> 5;
      float4 z = {0.f, 0.f, 0.f, 0.f};
      xl[f] = (rr < nr) ? reinterpret_cast<const float4*>(x + (size_t)r0 * HN)[f] : z;
    }
  }
  __syncthreads();

  float acc[16];
#pragma unroll
  for (int r = 0; r < 16; ++r) acc[r] = bo;

  const float4* xg = &xl[(g * 16) * 32];
#pragma unroll 8
  for (int k4 = 0; k4 < 32; ++k4) {
    const float4 wv = Wl[o * 32 + (k4 ^ (o & 7))];
#pragma unroll
    for (int r = 0; r < 16; ++r) {
      const float4 xv = xg[r * 32 + k4];
      acc[r] = fmaf(xv.x, wv.x, acc[r]);
      acc[r] = fmaf(xv.y, wv.y, acc[r]);
      acc[r] = fmaf(xv.z, wv.z, acc[r]);
      acc[r] = fmaf(xv.w, wv.w, acc[r]);
    }
  }

#pragma unroll
  for (int r = 0; r < 16; ++r) {
    const int row = r0 + g * 16 + r;
    if (row < nrows)
      m[(size_t)row * HN + o] = __float2bfloat16(fmaxf(acc[r], 0.f));
  }
}

// ---------------- degree histogram ----------------
__global__ void degree_k(const int* __restrict__ rows, int* __restrict__ deg,
                         int nedges) {
  for (int e = blockIdx.x * blockDim.x + threadIdx.x; e < nedges;
       e += gridDim.x * blockDim.x)
    atomicAdd(&deg[rows[e]], 1);
}

// ---------------- single-block exclusive scan -> rowptr, cursor ----------------
__global__ __launch_bounds__(1024) void scan_k(const int* __restrict__ deg,
                                               int* __restrict__ rowptr,
                                               int* __restrict__ cursor,
                                               int n) {
  __shared__ int part[1024];
  const int t = threadIdx.x;
  const int chunk = (n + 1023) / 1024;
  const int lo = t * chunk;
  const int hi = min(lo + chunk, n);
  int s = 0;
  for (int i = lo; i < hi; ++i) s += deg[i];
  part[t] = s;
  __syncthreads();
  for (int off = 1; off < 1024; off <<= 1) {
    int v = 0;
    if (t >= off) v = part[t - off];
    __syncthreads();
    if (t >= off) part[t] += v;
    __syncthreads();
  }
  int run = (t == 0) ? 0 : part[t - 1];
  for (int i = lo; i < hi; ++i) {
    rowptr[i] = run;
    cursor[i] = run;
    run += deg[i];
  }
  if (t == 1023) rowptr[n] = part[1023];
}

// ---------------- CSR fill ----------------
__global__ void fill_k(const int* __restrict__ rows,
                       const int* __restrict__ cols, int* __restrict__ cursor,
                       int* __restrict__ csr, int nedges) {
  for (int e = blockIdx.x * blockDim.x + threadIdx.x; e < nedges;
       e += gridDim.x * blockDim.x) {
    const int r = rows[e];
    const int pos = atomicAdd(&cursor[r], 1);
    csr[pos] = cols[e];
  }
}

// ---------------- gather + avg + residual + RMSNorm (fused) ----------------
// One wave per row; lane holds 2 columns. m rows read as 256 B contiguous
// bf16x2 per visit (L2/L3-resident). No atomics, no agg buffer.
__global__ __launch_bounds__(256) void gather_k(
    const __hip_bfloat162* __restrict__ m2, const int* __restrict__ rowptr,
    const int* __restrict__ csr, const float* __restrict__ x,
    const float* __restrict__ gamma, const float* __restrict__ beta,
    float* __restrict__ out, int nrows) {
  const int r = blockIdx.x * 4 + (threadIdx.x >> 6);
  if (r >= nrows) return;
  const int lane = threadIdx.x & 63;

  const int start = rowptr[r];
  const int end = rowptr[r + 1];
  float a0 = 0.f, a1 = 0.f;
  for (int base = start; base < end; base += 64) {
    const int nv = min(64, end - base);
    const int c = (base + lane < end) ? csr[base + lane] : 0;
    for (int j = 0; j < nv; ++j) {
      const int cc = __shfl(c, j);
      const __hip_bfloat162 v = m2[(size_t)cc * 64 + lane];
      a0 += __bfloat162float(v.x);
      a1 += __bfloat162float(v.y);
    }
  }

  const int d = end - start;
  const float inv_d = (d > 0) ? 1.f / (float)d : 1.f;
  const float2 xv = reinterpret_cast<const float2*>(x)[(size_t)r * 64 + lane];
  const float h0 = xv.x + a0 * inv_d;
  const float h1 = xv.y + a1 * inv_d;

  float ss = h0 * h0 + h1 * h1;
#pragma unroll
  for (int off = 1; off < 64; off <<= 1) ss += __shfl_xor(ss, off);
  const float invrms = rsqrtf(ss * (1.f / HN) + EPS);

  const float g0 = gamma[lane * 2], g1 = gamma[lane * 2 + 1];
  const float b0 = beta[lane * 2], b1 = beta[lane * 2 + 1];
  float2 o2;
  o2.x = h0 * invrms * g0 + b0;
  o2.y = h1 * invrms * g1 + b1;
  reinterpret_cast<float2*>(out)[(size_t)r * 64 + lane] = o2;
}

extern "C" void kernel_launch(void* const* d_in, const int* in_sizes, int n_in,
                              void* d_out, int out_size, void* d_ws,
                              size_t ws_size, hipStream_t stream) {
  const float* x = (const float*)d_in[0];
  const float* W = (const float*)d_in[1];
  const float* b = (const float*)d_in[2];
  const float* gamma = (const float*)d_in[3];
  const float* beta = (const float*)d_in[4];
  const int* rows = (const int*)d_in[5];
  const int* cols = (const int*)d_in[6];
  float* out = (float*)d_out;

  const int N = in_sizes[0] / HN;  // 100000
  const int E = in_sizes[5];       // 1600000

  // ws layout (all 256B-aligned): m_bf16 | deg | rowptr | cursor | csr
  char* p = (char*)d_ws;
  __hip_bfloat16* m = (__hip_bfloat16*)p;
  p += ((size_t)N * HN * sizeof(__hip_bfloat16) + 255) & ~(size_t)255;
  int* deg = (int*)p;
  p += ((size_t)N * sizeof(int) + 255) & ~(size_t)255;
  int* rowptr = (int*)p;
  p += ((size_t)(N + 1) * sizeof(int) + 255) & ~(size_t)255;
  int* cursor = (int*)p;
  p += ((size_t)N * sizeof(int) + 255) & ~(size_t)255;
  int* csr = (int*)p;

  hipMemsetAsync(deg, 0, (size_t)N * sizeof(int), stream);

  const int gemm_blocks = (N + 31) / 32;
  gemm_relu_k<<<gemm_blocks, 256, 0, stream>>>(x, W, b, m, N);
  degree_k<<<1024, 256, 0, stream>>>(rows, deg, E);
  scan_k<<<1, 1024, 0, stream>>>(deg, rowptr, cursor, N);
  fill_k<<<1024, 256, 0, stream>>>(rows, cols, cursor, csr, E);
  gather_k<<<(N + 3) / 4, 256, 0, stream>>>(
      (const __hip_bfloat162*)m, rowptr, csr, x, gamma, beta, out, N);
}

// Round 3
// 434.005 us; speedup vs baseline: 5.8136x; 1.5324x over previous
//
#include <hip/hip_runtime.h>
#include <hip/hip_bf16.h>

#define HN 128
#define EPS 1e-5f
#define SCHUNK 256  // scan elements per block

// ---------------- GEMM: m = relu(x @ W^T + b), output bf16 ----------------
__global__ __launch_bounds__(256) void gemm_relu_k(
    const float* __restrict__ x, const float* __restrict__ W,
    const float* __restrict__ bias, __hip_bfloat16* __restrict__ m,
    int nrows) {
  __shared__ float4 Wl[128 * 32];  // 64 KB, swizzled
  __shared__ float4 xl[32 * 32];   // 16 KB, 32 rows
  const int t = threadIdx.x;
  const int o = t & 127;
  const int g = t >> 7;

  for (int f = t; f < 128 * 32; f += 256) {
    const int ro = f >> 5, c = f & 31;
    Wl[ro * 32 + (c ^ (ro & 7))] = reinterpret_cast<const float4*>(W)[f];
  }
  const float bo = bias[o];

  const int r0 = blockIdx.x * 32;
  if (r0 >= nrows) return;
  const int nr = min(32, nrows - r0);

  if (nr == 32) {
    for (int f = t; f < 32 * 32; f += 256)
      xl[f] = reinterpret_cast<const float4*>(x + (size_t)r0 * HN)[f];
  } else {
    for (int f = t; f < 32 * 32; f += 256) {
      const int rr = f >> 5;
      float4 z = {0.f, 0.f, 0.f, 0.f};
      xl[f] = (rr < nr) ? reinterpret_cast<const float4*>(x + (size_t)r0 * HN)[f] : z;
    }
  }
  __syncthreads();

  float acc[16];
#pragma unroll
  for (int r = 0; r < 16; ++r) acc[r] = bo;

  const float4* xg = &xl[(g * 16) * 32];
#pragma unroll 8
  for (int k4 = 0; k4 < 32; ++k4) {
    const float4 wv = Wl[o * 32 + (k4 ^ (o & 7))];
#pragma unroll
    for (int r = 0; r < 16; ++r) {
      const float4 xv = xg[r * 32 + k4];
      acc[r] = fmaf(xv.x, wv.x, acc[r]);
      acc[r] = fmaf(xv.y, wv.y, acc[r]);
      acc[r] = fmaf(xv.z, wv.z, acc[r]);
      acc[r] = fmaf(xv.w, wv.w, acc[r]);
    }
  }

#pragma unroll
  for (int r = 0; r < 16; ++r) {
    const int row = r0 + g * 16 + r;
    if (row < nrows)
      m[(size_t)row * HN + o] = __float2bfloat16(fmaxf(acc[r], 0.f));
  }
}

// ---------------- degree histogram ----------------
__global__ void degree_k(const int* __restrict__ rows, int* __restrict__ deg,
                         int nedges) {
  for (int e = blockIdx.x * blockDim.x + threadIdx.x; e < nedges;
       e += gridDim.x * blockDim.x)
    atomicAdd(&deg[rows[e]], 1);
}

// ---------------- two-level scan ----------------
// 1) per-block sums of deg chunks
__global__ __launch_bounds__(SCHUNK) void blocksum_k(const int* __restrict__ deg,
                                                     int* __restrict__ bsum,
                                                     int n) {
  __shared__ int s[SCHUNK];
  const int i = blockIdx.x * SCHUNK + threadIdx.x;
  int v = (i < n) ? deg[i] : 0;
  s[threadIdx.x] = v;
  __syncthreads();
  for (int off = SCHUNK / 2; off > 0; off >>= 1) {
    if (threadIdx.x < off) s[threadIdx.x] += s[threadIdx.x + off];
    __syncthreads();
  }
  if (threadIdx.x == 0) bsum[blockIdx.x] = s[0];
}

// 2) single-block exclusive scan of block sums (nb <= 1024); writes rowptr[n]
__global__ __launch_bounds__(1024) void scan_bsums_k(int* __restrict__ bsum,
                                                     int* __restrict__ rowptr,
                                                     int nb, int n) {
  __shared__ int s[1024];
  const int t = threadIdx.x;
  int v = (t < nb) ? bsum[t] : 0;
  s[t] = v;
  __syncthreads();
  for (int off = 1; off < 1024; off <<= 1) {
    int u = 0;
    if (t >= off) u = s[t - off];
    __syncthreads();
    if (t >= off) s[t] += u;
    __syncthreads();
  }
  // exclusive: bsum[t] = sum of blocks < t
  if (t < nb) bsum[t] = (t == 0) ? 0 : s[t - 1];
  if (t == 0) rowptr[n] = s[1023];
}

// 3) intra-block exclusive scan + block offset -> rowptr, cursor
__global__ __launch_bounds__(SCHUNK) void rowptr_k(const int* __restrict__ deg,
                                                   const int* __restrict__ bsum,
                                                   int* __restrict__ rowptr,
                                                   int* __restrict__ cursor,
                                                   int n) {
  __shared__ int s[SCHUNK];
  const int i = blockIdx.x * SCHUNK + threadIdx.x;
  const int t = threadIdx.x;
  int v = (i < n) ? deg[i] : 0;
  s[t] = v;
  __syncthreads();
  for (int off = 1; off < SCHUNK; off <<= 1) {
    int u = 0;
    if (t >= off) u = s[t - off];
    __syncthreads();
    if (t >= off) s[t] += u;
    __syncthreads();
  }
  if (i < n) {
    const int excl = bsum[blockIdx.x] + s[t] - v;  // inclusive - self
    rowptr[i] = excl;
    cursor[i] = excl;
  }
}

// ---------------- CSR fill ----------------
__global__ void fill_k(const int* __restrict__ rows,
                       const int* __restrict__ cols, int* __restrict__ cursor,
                       int* __restrict__ csr, int nedges) {
  for (int e = blockIdx.x * blockDim.x + threadIdx.x; e < nedges;
       e += gridDim.x * blockDim.x) {
    const int r = rows[e];
    const int pos = atomicAdd(&cursor[r], 1);
    csr[pos] = cols[e];
  }
}

// ---------------- gather + avg + residual + RMSNorm (fused) ----------------
__global__ __launch_bounds__(256) void gather_k(
    const __hip_bfloat162* __restrict__ m2, const int* __restrict__ rowptr,
    const int* __restrict__ csr, const float* __restrict__ x,
    const float* __restrict__ gamma, const float* __restrict__ beta,
    float* __restrict__ out, int nrows) {
  const int r = blockIdx.x * 4 + (threadIdx.x >> 6);
  if (r >= nrows) return;
  const int lane = threadIdx.x & 63;

  const int start = rowptr[r];
  const int end = rowptr[r + 1];
  float a0 = 0.f, a1 = 0.f;
  for (int base = start; base < end; base += 64) {
    const int nv = min(64, end - base);
    const int c = (base + lane < end) ? csr[base + lane] : 0;
    for (int j = 0; j < nv; ++j) {
      const int cc = __shfl(c, j);
      const __hip_bfloat162 v = m2[(size_t)cc * 64 + lane];
      a0 += __bfloat162float(v.x);
      a1 += __bfloat162float(v.y);
    }
  }

  const int d = end - start;
  const float inv_d = (d > 0) ? 1.f / (float)d : 1.f;
  const float2 xv = reinterpret_cast<const float2*>(x)[(size_t)r * 64 + lane];
  const float h0 = xv.x + a0 * inv_d;
  const float h1 = xv.y + a1 * inv_d;

  float ss = h0 * h0 + h1 * h1;
#pragma unroll
  for (int off = 1; off < 64; off <<= 1) ss += __shfl_xor(ss, off);
  const float invrms = rsqrtf(ss * (1.f / HN) + EPS);

  const float g0 = gamma[lane * 2], g1 = gamma[lane * 2 + 1];
  const float b0 = beta[lane * 2], b1 = beta[lane * 2 + 1];
  float2 o2;
  o2.x = h0 * invrms * g0 + b0;
  o2.y = h1 * invrms * g1 + b1;
  reinterpret_cast<float2*>(out)[(size_t)r * 64 + lane] = o2;
}

extern "C" void kernel_launch(void* const* d_in, const int* in_sizes, int n_in,
                              void* d_out, int out_size, void* d_ws,
                              size_t ws_size, hipStream_t stream) {
  const float* x = (const float*)d_in[0];
  const float* W = (const float*)d_in[1];
  const float* b = (const float*)d_in[2];
  const float* gamma = (const float*)d_in[3];
  const float* beta = (const float*)d_in[4];
  const int* rows = (const int*)d_in[5];
  const int* cols = (const int*)d_in[6];
  float* out = (float*)d_out;

  const int N = in_sizes[0] / HN;  // 100000
  const int E = in_sizes[5];       // 1600000

  // ws layout: m_bf16 | deg | rowptr | cursor | bsum | csr
  char* p = (char*)d_ws;
  __hip_bfloat16* m = (__hip_bfloat16*)p;
  p += ((size_t)N * HN * sizeof(__hip_bfloat16) + 255) & ~(size_t)255;
  int* deg = (int*)p;
  p += ((size_t)N * sizeof(int) + 255) & ~(size_t)255;
  int* rowptr = (int*)p;
  p += ((size_t)(N + 1) * sizeof(int) + 255) & ~(size_t)255;
  int* cursor = (int*)p;
  p += ((size_t)N * sizeof(int) + 255) & ~(size_t)255;
  int* bsum = (int*)p;
  p += ((size_t)2048 * sizeof(int) + 255) & ~(size_t)255;
  int* csr = (int*)p;

  hipMemsetAsync(deg, 0, (size_t)N * sizeof(int), stream);

  const int nb = (N + SCHUNK - 1) / SCHUNK;  // 391 for N=100000 (<=1024)
  const int gemm_blocks = (N + 31) / 32;

  gemm_relu_k<<<gemm_blocks, 256, 0, stream>>>(x, W, b, m, N);
  degree_k<<<1024, 256, 0, stream>>>(rows, deg, E);
  blocksum_k<<<nb, SCHUNK, 0, stream>>>(deg, bsum, N);
  scan_bsums_k<<<1, 1024, 0, stream>>>(bsum, rowptr, nb, N);
  rowptr_k<<<nb, SCHUNK, 0, stream>>>(deg, bsum, rowptr, cursor, N);
  fill_k<<<1024, 256, 0, stream>>>(rows, cols, cursor, csr, E);
  gather_k<<<(N + 3) / 4, 256, 0, stream>>>(
      (const __hip_bfloat162*)m, rowptr, csr, x, gamma, beta, out, N);
}